// Round 11
// baseline (362.998 us; speedup 1.0000x reference)
//
#include <hip/hip_runtime.h>
#include <hip/hip_bf16.h>
#include <math.h>

typedef __attribute__((ext_vector_type(4))) float f32x4;
typedef __attribute__((ext_vector_type(8))) short short8;
typedef __attribute__((ext_vector_type(4))) short short4v;

#define H_DIM 256
#define SQ_DIM 256
#define SK_DIM 512
#define E_DIM 512
#define B_DIM 2

// ---------------------------------------------------------------------------
// split_cast: query/key fp32 [m][512] -> A1 bf16 [1536][1024] rows = [hi|lo]
// ---------------------------------------------------------------------------
__global__ __launch_bounds__(256) void split_cast(const float* __restrict__ query,
                                                  const float* __restrict__ key,
                                                  __hip_bfloat16* __restrict__ A1)
{
    int gid = blockIdx.x * 256 + threadIdx.x;    // 0..196607, one f32x4 each
    int m  = gid >> 7;                            // row 0..1535
    int kq = gid & 127;                           // f32x4 index within row
    const float* src = (m < 512) ? query + (size_t)m * 512
                                 : key + (size_t)(m - 512) * 512;
    f32x4 v = *(const f32x4*)(src + kq * 4);
    short4v hv, lv;
    #pragma unroll
    for (int j = 0; j < 4; ++j) {
        __hip_bfloat16 h = __float2bfloat16(v[j]);
        float lf = v[j] - __bfloat162float(h);
        __hip_bfloat16 l = __float2bfloat16(lf);
        hv[j] = __builtin_bit_cast(short, h);
        lv[j] = __builtin_bit_cast(short, l);
    }
    *(short4v*)(A1 + (size_t)m * 1024 + kq * 4) = hv;
    *(short4v*)(A1 + (size_t)m * 1024 + 512 + kq * 4) = lv;
}

// ---------------------------------------------------------------------------
// transpose_split: 8 transpose jobs in one launch.
//  jobs 0-5: W [K][256] fp32 -> T [256][2K] bf16 rows = [hi|lo] (split)
//  jobs 6-7: W1/W2 [256][256] fp32 -> W*T [256][256] bf16 (plain, pair-MLP)
// ---------------------------------------------------------------------------
__global__ __launch_bounds__(256) void transpose_split(
    const float* __restrict__ Wqe, const float* __restrict__ Wke,
    const float* __restrict__ W0,  const float* __restrict__ Wv1,
    const float* __restrict__ W1,  const float* __restrict__ W2,
    __hip_bfloat16* __restrict__ Benc, __hip_bfloat16* __restrict__ Bproj,
    __hip_bfloat16* __restrict__ W1T,  __hip_bfloat16* __restrict__ W2T)
{
    __shared__ float tile[64][65];
    const float* S = nullptr; __hip_bfloat16* D = nullptr; int KJ = 256;
    bool split = true;
    switch (blockIdx.y) {
        case 0: S = Wqe;             D = Benc;                          KJ = 512; break;
        case 1: S = Wke;             D = Benc + 256 * 1024;             KJ = 512; break;
        case 2: S = W0;              D = Bproj;                         KJ = 256; break;
        case 3: S = Wv1;             D = Bproj + 256 * 512;             KJ = 256; break;
        case 4: S = W0 + 256 * 256;  D = Bproj + 512 * 512;             KJ = 256; break;
        case 5: S = Wv1 + 256 * 256; D = Bproj + 512 * 512 + 256 * 512; KJ = 256; break;
        case 6: S = W1;              D = W1T;  KJ = 256; split = false; break;
        case 7: S = W2;              D = W2T;  KJ = 256; split = false; break;
    }
    const int dstStride = split ? 2 * KJ : KJ;
    const int ntile = 4 * (KJ >> 6);
    const int x = blockIdx.x;
    if (x >= ntile) return;
    const int tx = x & 3, ty = x >> 2;
    const int k0 = ty * 64, n0 = tx * 64;
    const int t = threadIdx.x;
    #pragma unroll
    for (int i = 0; i < 16; ++i) {
        int r = (t >> 6) + i * 4;
        int c = t & 63;
        tile[r][c] = S[(size_t)(k0 + r) * 256 + n0 + c];
    }
    __syncthreads();
    #pragma unroll
    for (int i = 0; i < 16; ++i) {
        int r = (t >> 6) + i * 4;   // n-local
        int c = t & 63;             // k-local
        float v = tile[c][r];
        __hip_bfloat16 h = __float2bfloat16(v);
        D[(size_t)(n0 + r) * dstStride + k0 + c] = h;
        if (split) {
            float lf = v - __bfloat162float(h);
            D[(size_t)(n0 + r) * dstStride + KJ + k0 + c] = __float2bfloat16(lf);
        }
    }
}

// ---------------------------------------------------------------------------
// gemm3: split-bf16 (3-MFMA) NT GEMM.  C[m,n] = sum_k A[m,k] * B^T[n,k]
// A planes [M][2K] (hi|lo per row), B planes [..][2K]; B0 for m<512, B1 else.
// Tile 64x64 / 256 thr / 4 waves (2m x 2n).  LDS 2 x 16KB double-buffered.
// SPLIT_OUT: out = relu(C + bias) split to bf16 hi/lo [M][512] (bias0 m<512).
// else: fp32 out, cols <256 -> outF0[m][n], else outF1[m][n-256], no bias.
// ---------------------------------------------------------------------------
template<int KD, bool SPLIT_OUT>
__global__ __launch_bounds__(256) void gemm3(
    const __hip_bfloat16* __restrict__ Apl,
    const __hip_bfloat16* __restrict__ B0,
    const __hip_bfloat16* __restrict__ B1,
    const float* __restrict__ bias0, const float* __restrict__ bias1,
    __hip_bfloat16* __restrict__ outS,
    float* __restrict__ outF0, float* __restrict__ outF1)
{
    __shared__ char smem[32768];
    const int t = threadIdx.x, lane = t & 63, wave = t >> 6;
    const int wm = wave >> 1, wn = wave & 1;
    const int m0 = blockIdx.y * 64, n0 = blockIdx.x * 64;
    const __hip_bfloat16* Arow = Apl + (size_t)m0 * (2 * KD);
    const __hip_bfloat16* Brow = ((m0 < 512) ? B0 : B1) + (size_t)n0 * (2 * KD);

    // stage K-chunk c (32 k) of A+B hi/lo planes: 256 rows x 64B, swizzled src
    auto stage = [&](int c) {
        char* wb = smem + ((c & 1) << 14);
        const int k0 = c * 32;
        #pragma unroll
        for (int i = 0; i < 4; ++i) {
            int u = wave * 64 + lane + i * 256;   // 16B unit 0..1023
            int r = u >> 2;                        // LDS row 0..255
            int sl = (u & 3) ^ ((r >> 1) & 3);     // inverse swizzle on source
            int isB = r >> 7;
            int rr = r & 127;
            const __hip_bfloat16* base = isB ? Brow : Arow;
            const __hip_bfloat16* gp = base + (size_t)(rr >> 1) * (2 * KD)
                                       + (rr & 1) * KD + k0 + sl * 8;
            char* lp = wb + (wave * 64 + i * 256) * 16;   // wave-uniform base
            __builtin_amdgcn_global_load_lds((const void*)gp, (void*)lp, 16, 0, 0);
        }
    };

    stage(0);
    __syncthreads();   // drain vmcnt(0): chunk-0 DMA landed before c=0 ds_reads
    f32x4 acc[2][2];
    #pragma unroll
    for (int i = 0; i < 2; ++i)
        #pragma unroll
        for (int j = 0; j < 2; ++j) acc[i][j] = 0.f;

    const int NCH = KD / 32;
    for (int c = 0; c < NCH; ++c) {
        if (c + 1 < NCH) stage(c + 1);
        const char* wb = smem + ((c & 1) << 14);
        short8 ah[2], al[2];
        #pragma unroll
        for (int nt = 0; nt < 2; ++nt) {
            int n = wn * 32 + nt * 16 + (lane & 15);
            int rh = 128 + 2 * n, rl = rh + 1;
            ah[nt] = *(const short8*)(wb + rh * 64 + (((lane >> 4) ^ ((rh >> 1) & 3)) << 4));
            al[nt] = *(const short8*)(wb + rl * 64 + (((lane >> 4) ^ ((rl >> 1) & 3)) << 4));
        }
        #pragma unroll
        for (int mt = 0; mt < 2; ++mt) {
            int m = wm * 32 + mt * 16 + (lane & 15);
            int rh = 2 * m, rl = rh + 1;
            short8 bh = *(const short8*)(wb + rh * 64 + (((lane >> 4) ^ ((rh >> 1) & 3)) << 4));
            short8 bl = *(const short8*)(wb + rl * 64 + (((lane >> 4) ^ ((rl >> 1) & 3)) << 4));
            #pragma unroll
            for (int nt = 0; nt < 2; ++nt) {
                acc[mt][nt] = __builtin_amdgcn_mfma_f32_16x16x32_bf16(ah[nt], bh, acc[mt][nt], 0, 0, 0);
                acc[mt][nt] = __builtin_amdgcn_mfma_f32_16x16x32_bf16(al[nt], bh, acc[mt][nt], 0, 0, 0);
                acc[mt][nt] = __builtin_amdgcn_mfma_f32_16x16x32_bf16(ah[nt], bl, acc[mt][nt], 0, 0, 0);
            }
        }
        __syncthreads();
    }

    // epilogue: acc layout col=lane&15 -> m, row=(lane>>4)*4+j -> n
    #pragma unroll
    for (int mt = 0; mt < 2; ++mt) {
        int m = m0 + wm * 32 + mt * 16 + (lane & 15);
        #pragma unroll
        for (int nt = 0; nt < 2; ++nt) {
            int nb = n0 + wn * 32 + nt * 16 + ((lane >> 4) << 2);
            if (SPLIT_OUT) {
                const float* bias = (m0 < 512) ? bias0 : bias1;
                f32x4 bv = *(const f32x4*)(bias + nb);
                short4v hv, lv;
                #pragma unroll
                for (int j = 0; j < 4; ++j) {
                    float v = fmaxf(acc[mt][nt][j] + bv[j], 0.f);
                    __hip_bfloat16 h = __float2bfloat16(v);
                    float lf = v - __bfloat162float(h);
                    hv[j] = __builtin_bit_cast(short, h);
                    lv[j] = __builtin_bit_cast(short, __float2bfloat16(lf));
                }
                *(short4v*)(outS + (size_t)m * 512 + nb) = hv;
                *(short4v*)(outS + (size_t)m * 512 + 256 + nb) = lv;
            } else {
                float* o = (nb < 256) ? outF0 + (size_t)m * 256 + nb
                                      : outF1 + (size_t)m * 256 + (nb - 256);
                *(f32x4*)o = acc[mt][nt];
            }
        }
    }
}

// ---------------------------------------------------------------------------
// Main fused pair kernel, v6b: v6 structure (small blocks, static LDS, W from
// L2) with the spill fixed.  launch_bounds(256,2): arg2=4 empirically caps
// VGPR at 64 -> acc[4][4] spills to scratch (r5: 125 MB, r10: 24 MB writes).
// Block = (b, q, 64 k), 256 thr = 4 waves; wave wn owns a 64-n slice.
// LDS = static 32 KB -> 4 blocks/CU measured (occupancy 43%, r10).
// W frags direct from L2 (XCD-resident, kt pinned by idx&7).  5 barriers.
// hbuf: [64 m][256 k] bf16, byte addr (m*512 + k*2) ^ ((m&7)<<4)
// ---------------------------------------------------------------------------
__global__ __launch_bounds__(256, 2) void pair_main(
    const float* __restrict__ qp, const float* __restrict__ kp,
    const float* __restrict__ qv, const float* __restrict__ kv,
    const __hip_bfloat16* __restrict__ W1T, const __hip_bfloat16* __restrict__ W2T,
    const float* __restrict__ b0, const float* __restrict__ b1,
    const float* __restrict__ b2, const float* __restrict__ Wf,
    const float* __restrict__ bf_, const float* __restrict__ bv1,
    const float* __restrict__ Wv2, const float* __restrict__ bv2,
    float* __restrict__ out)
{
    __shared__ char hbuf[32768];

    const int t    = threadIdx.x;
    const int lane = t & 63, wn = t >> 6;      // wave = n-slice owner
    const int idx  = blockIdx.x;
    const int kt   = idx & 7;                  // low 3 bits -> XCD-pinned
    const int b    = (idx >> 3) & 1;
    const int q    = idx >> 4;                 // 0..255
    const int k0g  = kt * 64;

    const float* qprow  = qp + (size_t)(b * SQ_DIM + q) * H_DIM;
    const float* kprows = kp + (size_t)(b * SK_DIM + k0g) * H_DIM;

    // ---- h0 = relu(qp + kp + b0) -> hbuf (bf16, swizzled) ----
    #pragma unroll
    for (int i = 0; i < 8; ++i) {
        int cidx = t + 256 * i;
        int row  = cidx >> 5;     // 0..63
        int c8   = cidx & 31;     // 8-elem group
        const float* kr = kprows + row * H_DIM + c8 * 8;
        f32x4 k0v = *(const f32x4*)(kr);
        f32x4 k1v = *(const f32x4*)(kr + 4);
        f32x4 q0v = *(const f32x4*)(qprow + c8 * 8);
        f32x4 q1v = *(const f32x4*)(qprow + c8 * 8 + 4);
        f32x4 z0  = *(const f32x4*)(b0 + c8 * 8);
        f32x4 z1  = *(const f32x4*)(b0 + c8 * 8 + 4);
        short8 pk;
        #pragma unroll
        for (int j = 0; j < 4; ++j) {
            float v = fmaxf(k0v[j] + q0v[j] + z0[j], 0.f);
            float w = fmaxf(k1v[j] + q1v[j] + z1[j], 0.f);
            __hip_bfloat16 hv = __float2bfloat16(v);
            __hip_bfloat16 hw = __float2bfloat16(w);
            pk[j]     = __builtin_bit_cast(short, hv);
            pk[j + 4] = __builtin_bit_cast(short, hw);
        }
        int addr = (row * 512 + c8 * 16) ^ ((row & 7) << 4);
        *(short8*)(hbuf + addr) = pk;
    }
    __syncthreads();   // (1) h0 visible

    f32x4 acc[4][4];
    #pragma unroll
    for (int i = 0; i < 4; ++i)
        #pragma unroll
        for (int j = 0; j < 4; ++j)
            acc[i][j] = 0.f;

    // layer GEMM: W frags from L2, h frags from LDS, no barriers
    auto gemm_layer = [&](const __hip_bfloat16* __restrict__ Wsrc) {
        #pragma unroll
        for (int c = 0; c < 8; ++c) {
            short8 afrag[4], bfrag[4];
            #pragma unroll
            for (int nt = 0; nt < 4; ++nt) {
                int n = 64 * wn + 16 * nt + (lane & 15);
                afrag[nt] = *(const short8*)(Wsrc + (size_t)n * H_DIM
                                             + c * 32 + (lane >> 4) * 8);
            }
            #pragma unroll
            for (int mt = 0; mt < 4; ++mt) {
                int m = 16 * mt + (lane & 15);
                int addr = (m * 512 + c * 64 + ((lane >> 4) * 16)) ^ ((m & 7) << 4);
                bfrag[mt] = *(const short8*)(hbuf + addr);
            }
            #pragma unroll
            for (int mt = 0; mt < 4; ++mt)
                #pragma unroll
                for (int nt = 0; nt < 4; ++nt)
                    acc[mt][nt] = __builtin_amdgcn_mfma_f32_16x16x32_bf16(
                        afrag[nt], bfrag[mt], acc[mt][nt], 0, 0, 0);
        }
    };

    // ---- layer 1 ----
    gemm_layer(W1T);
    __syncthreads();   // (2) all waves done reading h0 before overwrite

    // ---- h1 = relu(D + b1) -> hbuf (wave wn writes its 64-n slice) ----
    #pragma unroll
    for (int mt = 0; mt < 4; ++mt) {
        int m = 16 * mt + (lane & 15);
        #pragma unroll
        for (int nt = 0; nt < 4; ++nt) {
            int n0_ = 64 * wn + 16 * nt + ((lane >> 4) << 2);
            f32x4 bias = *(const f32x4*)(b1 + n0_);
            short4v pk;
            #pragma unroll
            for (int j = 0; j < 4; ++j) {
                float v = fmaxf(acc[mt][nt][j] + bias[j], 0.f);
                __hip_bfloat16 hv = __float2bfloat16(v);
                pk[j] = __builtin_bit_cast(short, hv);
            }
            int addr = (m * 512 + n0_ * 2) ^ ((m & 7) << 4);
            *(short4v*)(hbuf + addr) = pk;
            acc[mt][nt] = 0.f;
        }
    }
    __syncthreads();   // (3) h1 visible

    // ---- layer 2 ----
    gemm_layer(W2T);

    // ---- logits: sum_n relu(h2 + b2) * Wf  (+ bf) ----
    float p[4];
    #pragma unroll
    for (int mt = 0; mt < 4; ++mt) {
        float s = 0.f;
        #pragma unroll
        for (int nt = 0; nt < 4; ++nt) {
            int n0_ = 64 * wn + 16 * nt + ((lane >> 4) << 2);
            f32x4 wf   = *(const f32x4*)(Wf + n0_);
            f32x4 bias = *(const f32x4*)(b2 + n0_);
            #pragma unroll
            for (int j = 0; j < 4; ++j)
                s += fmaxf(acc[mt][nt][j] + bias[j], 0.f) * wf[j];
        }
        s += __shfl_xor(s, 16);
        s += __shfl_xor(s, 32);
        p[mt] = s;
    }

    __syncthreads();   // (4) all hbuf reads done before lpart overwrite
    float* lpart = (float*)hbuf;
    if (lane < 16) {
        #pragma unroll
        for (int mt = 0; mt < 4; ++mt)
            lpart[(mt * 16 + lane) * 4 + wn] = p[mt];
    }
    __syncthreads();   // (5)

    const size_t obase = (size_t)(b * SQ_DIM + q) * SK_DIM + k0g;
    if (t < 64) {
        f32x4 v = *(const f32x4*)(lpart + t * 4);
        out[obase + t] = v[0] + v[1] + v[2] + v[3] + bf_[0];
    }

    // ---- variance: softplus(sum_c relu(qv+kv+bv1)*Wv2 + bv2), fp32 ----
    {
        int r = t >> 2, s4 = t & 3;   // r 0..63
        const float* qvrow = qv + (size_t)(b * SQ_DIM + q) * H_DIM;
        const float* kvrow = kv + (size_t)(b * SK_DIM + k0g + r) * H_DIM;
        float a = 0.f;
        #pragma unroll
        for (int i = 0; i < 16; ++i) {
            int cidx = s4 * 64 + i * 4;
            f32x4 x  = *(const f32x4*)(qvrow + cidx);
            f32x4 y  = *(const f32x4*)(kvrow + cidx);
            f32x4 bb = *(const f32x4*)(bv1 + cidx);
            f32x4 wv = *(const f32x4*)(Wv2 + cidx);
            #pragma unroll
            for (int j = 0; j < 4; ++j)
                a += fmaxf(x[j] + y[j] + bb[j], 0.f) * wv[j];
        }
        a += __shfl_xor(a, 1);
        a += __shfl_xor(a, 2);
        if (s4 == 0) {
            float xx = a + bv2[0];
            float sp = (xx > 20.f) ? xx : log1pf(expf(xx));
            out[(size_t)B_DIM * SQ_DIM * SK_DIM + obase + r] = sp;
        }
    }
}

// ---------------------------------------------------------------------------
extern "C" void kernel_launch(void* const* d_in, const int* in_sizes, int n_in,
                              void* d_out, int out_size, void* d_ws, size_t ws_size,
                              hipStream_t stream)
{
    (void)in_sizes; (void)n_in; (void)out_size; (void)ws_size;

    const float* query = (const float*)d_in[0];
    const float* key   = (const float*)d_in[1];
    const float* Wqe   = (const float*)d_in[2];
    const float* bqe   = (const float*)d_in[3];
    const float* Wke   = (const float*)d_in[4];
    const float* bke   = (const float*)d_in[5];
    const float* W0    = (const float*)d_in[6];
    const float* b0    = (const float*)d_in[7];
    const float* W1    = (const float*)d_in[8];
    const float* b1    = (const float*)d_in[9];
    const float* W2    = (const float*)d_in[10];
    const float* b2    = (const float*)d_in[11];
    const float* Wf    = (const float*)d_in[12];
    const float* bf    = (const float*)d_in[13];
    const float* Wv1   = (const float*)d_in[14];
    const float* bv1   = (const float*)d_in[15];
    const float* Wv2   = (const float*)d_in[16];
    const float* bv2   = (const float*)d_in[17];
    float* out = (float*)d_out;

    char* ws = (char*)d_ws;
    // prep buffers (A1 region later reused by qpkp/qvkv — disjoint lifetimes)
    __hip_bfloat16* A1    = (__hip_bfloat16*)(ws);                 // 1536x1024 bf16 (3 MB)
    __hip_bfloat16* Aq    = (__hip_bfloat16*)(ws + 3145728);       // 1536x512 bf16 (1.5 MB)
    __hip_bfloat16* Benc  = (__hip_bfloat16*)(ws + 4718592);       // 2x256x1024 bf16 (1 MB)
    __hip_bfloat16* Bproj = (__hip_bfloat16*)(ws + 5767168);       // 2x512x512 bf16 (1 MB)
    __hip_bfloat16* W1T   = (__hip_bfloat16*)(ws + 6815744);       // 256x256 bf16
    __hip_bfloat16* W2T   = (__hip_bfloat16*)(ws + 6946816);       // 256x256 bf16
    float* qpkp = (float*)(ws);                                    // 1536x256 f32 (aliases A1)
    float* qvkv = (float*)(ws + 1572864);                          // 1536x256 f32

    const float* qp = qpkp;
    const float* kp = qpkp + 512 * 256;
    const float* qv = qvkv;
    const float* kv = qvkv + 512 * 256;

    transpose_split<<<dim3(32, 8), 256, 0, stream>>>(Wqe, Wke, W0, Wv1, W1, W2,
                                                     Benc, Bproj, W1T, W2T);
    split_cast<<<dim3(768), 256, 0, stream>>>(query, key, A1);
    // encoders: relu(A @ Wenc^T + bias) -> Aq (bf16 hi/lo)
    gemm3<512, true><<<dim3(4, 24), 256, 0, stream>>>(
        A1, Benc, Benc + 256 * 1024, bqe, bke, Aq, nullptr, nullptr);
    // projections: qpkp | qvkv (fp32), no bias
    gemm3<256, false><<<dim3(8, 24), 256, 0, stream>>>(
        Aq, Bproj, Bproj + 512 * 512, nullptr, nullptr, nullptr, qpkp, qvkv);
    // fused pair MLP + variance
    pair_main<<<dim3(4096), 256, 0, stream>>>(qp, kp, qv, kv, W1T, W2T,
                                              b0, b1, b2, Wf, bf, bv1, Wv2, bv2, out);
}

// Round 13
// 306.492 us; speedup vs baseline: 1.1844x; 1.1844x over previous
//
#include <hip/hip_runtime.h>
#include <hip/hip_bf16.h>
#include <math.h>

typedef __attribute__((ext_vector_type(4))) float f32x4;
typedef __attribute__((ext_vector_type(8))) short short8;
typedef __attribute__((ext_vector_type(4))) short short4v;

#define H_DIM 256
#define SQ_DIM 256
#define SK_DIM 512
#define E_DIM 512
#define B_DIM 2

#define RAW_BARRIER()  __builtin_amdgcn_s_barrier()
#define SCHED_FENCE()  __builtin_amdgcn_sched_barrier(0)
#define WAIT_VMCNT_2() do { asm volatile("s_waitcnt vmcnt(2)" ::: "memory"); \
                            __builtin_amdgcn_sched_barrier(0); } while (0)
#define WAIT_VMCNT_0() do { asm volatile("s_waitcnt vmcnt(0)" ::: "memory"); \
                            __builtin_amdgcn_sched_barrier(0); } while (0)
#define WAIT_LGKM_0()  do { asm volatile("s_waitcnt lgkmcnt(0)" ::: "memory"); \
                            __builtin_amdgcn_sched_barrier(0); } while (0)

// ---------------------------------------------------------------------------
// split_cast: query/key fp32 [m][512] -> A1 bf16 [1536][1024] rows = [hi|lo]
// ---------------------------------------------------------------------------
__global__ __launch_bounds__(256) void split_cast(const float* __restrict__ query,
                                                  const float* __restrict__ key,
                                                  __hip_bfloat16* __restrict__ A1)
{
    int gid = blockIdx.x * 256 + threadIdx.x;    // 0..196607, one f32x4 each
    int m  = gid >> 7;                            // row 0..1535
    int kq = gid & 127;                           // f32x4 index within row
    const float* src = (m < 512) ? query + (size_t)m * 512
                                 : key + (size_t)(m - 512) * 512;
    f32x4 v = *(const f32x4*)(src + kq * 4);
    short4v hv, lv;
    #pragma unroll
    for (int j = 0; j < 4; ++j) {
        __hip_bfloat16 h = __float2bfloat16(v[j]);
        float lf = v[j] - __bfloat162float(h);
        __hip_bfloat16 l = __float2bfloat16(lf);
        hv[j] = __builtin_bit_cast(short, h);
        lv[j] = __builtin_bit_cast(short, l);
    }
    *(short4v*)(A1 + (size_t)m * 1024 + kq * 4) = hv;
    *(short4v*)(A1 + (size_t)m * 1024 + 512 + kq * 4) = lv;
}

// ---------------------------------------------------------------------------
// transpose_split: 8 transpose jobs in one launch.
//  jobs 0-5: W [K][256] fp32 -> T [256][2K] bf16 rows = [hi|lo] (split)
//  jobs 6-7: W1/W2 [256][256] fp32 -> W*T [256][256] bf16 (plain, pair-MLP)
// ---------------------------------------------------------------------------
__global__ __launch_bounds__(256) void transpose_split(
    const float* __restrict__ Wqe, const float* __restrict__ Wke,
    const float* __restrict__ W0,  const float* __restrict__ Wv1,
    const float* __restrict__ W1,  const float* __restrict__ W2,
    __hip_bfloat16* __restrict__ Benc, __hip_bfloat16* __restrict__ Bproj,
    __hip_bfloat16* __restrict__ W1T,  __hip_bfloat16* __restrict__ W2T)
{
    __shared__ float tile[64][65];
    const float* S = nullptr; __hip_bfloat16* D = nullptr; int KJ = 256;
    bool split = true;
    switch (blockIdx.y) {
        case 0: S = Wqe;             D = Benc;                          KJ = 512; break;
        case 1: S = Wke;             D = Benc + 256 * 1024;             KJ = 512; break;
        case 2: S = W0;              D = Bproj;                         KJ = 256; break;
        case 3: S = Wv1;             D = Bproj + 256 * 512;             KJ = 256; break;
        case 4: S = W0 + 256 * 256;  D = Bproj + 512 * 512;             KJ = 256; break;
        case 5: S = Wv1 + 256 * 256; D = Bproj + 512 * 512 + 256 * 512; KJ = 256; break;
        case 6: S = W1;              D = W1T;  KJ = 256; split = false; break;
        case 7: S = W2;              D = W2T;  KJ = 256; split = false; break;
    }
    const int dstStride = split ? 2 * KJ : KJ;
    const int ntile = 4 * (KJ >> 6);
    const int x = blockIdx.x;
    if (x >= ntile) return;
    const int tx = x & 3, ty = x >> 2;
    const int k0 = ty * 64, n0 = tx * 64;
    const int t = threadIdx.x;
    #pragma unroll
    for (int i = 0; i < 16; ++i) {
        int r = (t >> 6) + i * 4;
        int c = t & 63;
        tile[r][c] = S[(size_t)(k0 + r) * 256 + n0 + c];
    }
    __syncthreads();
    #pragma unroll
    for (int i = 0; i < 16; ++i) {
        int r = (t >> 6) + i * 4;   // n-local
        int c = t & 63;             // k-local
        float v = tile[c][r];
        __hip_bfloat16 h = __float2bfloat16(v);
        D[(size_t)(n0 + r) * dstStride + k0 + c] = h;
        if (split) {
            float lf = v - __bfloat162float(h);
            D[(size_t)(n0 + r) * dstStride + KJ + k0 + c] = __float2bfloat16(lf);
        }
    }
}

// ---------------------------------------------------------------------------
// gemm3: split-bf16 (3-MFMA) NT GEMM.  C[m,n] = sum_k A[m,k] * B^T[n,k]
// ---------------------------------------------------------------------------
template<int KD, bool SPLIT_OUT>
__global__ __launch_bounds__(256) void gemm3(
    const __hip_bfloat16* __restrict__ Apl,
    const __hip_bfloat16* __restrict__ B0,
    const __hip_bfloat16* __restrict__ B1,
    const float* __restrict__ bias0, const float* __restrict__ bias1,
    __hip_bfloat16* __restrict__ outS,
    float* __restrict__ outF0, float* __restrict__ outF1)
{
    __shared__ char smem[32768];
    const int t = threadIdx.x, lane = t & 63, wave = t >> 6;
    const int wm = wave >> 1, wn = wave & 1;
    const int m0 = blockIdx.y * 64, n0 = blockIdx.x * 64;
    const __hip_bfloat16* Arow = Apl + (size_t)m0 * (2 * KD);
    const __hip_bfloat16* Brow = ((m0 < 512) ? B0 : B1) + (size_t)n0 * (2 * KD);

    auto stage = [&](int c) {
        char* wb = smem + ((c & 1) << 14);
        const int k0 = c * 32;
        #pragma unroll
        for (int i = 0; i < 4; ++i) {
            int u = wave * 64 + lane + i * 256;   // 16B unit 0..1023
            int r = u >> 2;                        // LDS row 0..255
            int sl = (u & 3) ^ ((r >> 1) & 3);     // inverse swizzle on source
            int isB = r >> 7;
            int rr = r & 127;
            const __hip_bfloat16* base = isB ? Brow : Arow;
            const __hip_bfloat16* gp = base + (size_t)(rr >> 1) * (2 * KD)
                                       + (rr & 1) * KD + k0 + sl * 8;
            char* lp = wb + (wave * 64 + i * 256) * 16;   // wave-uniform base
            __builtin_amdgcn_global_load_lds((const void*)gp, (void*)lp, 16, 0, 0);
        }
    };

    stage(0);
    __syncthreads();   // drain vmcnt(0): chunk-0 DMA landed before c=0 ds_reads
    f32x4 acc[2][2];
    #pragma unroll
    for (int i = 0; i < 2; ++i)
        #pragma unroll
        for (int j = 0; j < 2; ++j) acc[i][j] = 0.f;

    const int NCH = KD / 32;
    for (int c = 0; c < NCH; ++c) {
        if (c + 1 < NCH) stage(c + 1);
        const char* wb = smem + ((c & 1) << 14);
        short8 ah[2], al[2];
        #pragma unroll
        for (int nt = 0; nt < 2; ++nt) {
            int n = wn * 32 + nt * 16 + (lane & 15);
            int rh = 128 + 2 * n, rl = rh + 1;
            ah[nt] = *(const short8*)(wb + rh * 64 + (((lane >> 4) ^ ((rh >> 1) & 3)) << 4));
            al[nt] = *(const short8*)(wb + rl * 64 + (((lane >> 4) ^ ((rl >> 1) & 3)) << 4));
        }
        #pragma unroll
        for (int mt = 0; mt < 2; ++mt) {
            int m = wm * 32 + mt * 16 + (lane & 15);
            int rh = 2 * m, rl = rh + 1;
            short8 bh = *(const short8*)(wb + rh * 64 + (((lane >> 4) ^ ((rh >> 1) & 3)) << 4));
            short8 bl = *(const short8*)(wb + rl * 64 + (((lane >> 4) ^ ((rl >> 1) & 3)) << 4));
            #pragma unroll
            for (int nt = 0; nt < 2; ++nt) {
                acc[mt][nt] = __builtin_amdgcn_mfma_f32_16x16x32_bf16(ah[nt], bh, acc[mt][nt], 0, 0, 0);
                acc[mt][nt] = __builtin_amdgcn_mfma_f32_16x16x32_bf16(al[nt], bh, acc[mt][nt], 0, 0, 0);
                acc[mt][nt] = __builtin_amdgcn_mfma_f32_16x16x32_bf16(ah[nt], bl, acc[mt][nt], 0, 0, 0);
            }
        }
        __syncthreads();
    }

    #pragma unroll
    for (int mt = 0; mt < 2; ++mt) {
        int m = m0 + wm * 32 + mt * 16 + (lane & 15);
        #pragma unroll
        for (int nt = 0; nt < 2; ++nt) {
            int nb = n0 + wn * 32 + nt * 16 + ((lane >> 4) << 2);
            if (SPLIT_OUT) {
                const float* bias = (m0 < 512) ? bias0 : bias1;
                f32x4 bv = *(const f32x4*)(bias + nb);
                short4v hv, lv;
                #pragma unroll
                for (int j = 0; j < 4; ++j) {
                    float v = fmaxf(acc[mt][nt][j] + bv[j], 0.f);
                    __hip_bfloat16 h = __float2bfloat16(v);
                    float lf = v - __bfloat162float(h);
                    hv[j] = __builtin_bit_cast(short, h);
                    lv[j] = __builtin_bit_cast(short, __float2bfloat16(lf));
                }
                *(short4v*)(outS + (size_t)m * 512 + nb) = hv;
                *(short4v*)(outS + (size_t)m * 512 + 256 + nb) = lv;
            } else {
                float* o = (nb < 256) ? outF0 + (size_t)m * 256 + nb
                                      : outF1 + (size_t)m * 256 + (nb - 256);
                *(f32x4*)o = acc[mt][nt];
            }
        }
    }
}

// ---------------------------------------------------------------------------
// Main fused pair kernel, v7b: counted-vmcnt pipeline, CROSS-WAVE-SAFE.
// v7 BUG: vmcnt is per-wave but wbuf rows are consumed cross-wave; v7 waited
// AFTER the barrier, so wave B could read wave A's rows before A's DMA
// landed (absmax 258).  FIX: each wave waits vmcnt(2) BEFORE the trailing
// barrier -- waves are symmetric, so post-barrier buf g+1 is fully landed.
// body(g): read buf g -> MFMA -> stage(g+2) -> vmcnt(2) -> lgkm0 -> barrier.
// stage(g+2) stays in flight across the barrier (never drained to 0 except
// at the tail).  3-slot wbuf ring: writer of buf (g+2)%3 is 2 barriers past
// its last reader (body(g-1), lgkm-drained).
// hbuf:  [128 m][256 k] bf16, byte addr (m*512 + k*2) ^ ((m&7)<<4)
// wbuf:  [256 n][4 slot][16B], slot_lds = slot_log ^ ((n>>1)&3)
// ---------------------------------------------------------------------------
__global__ __launch_bounds__(512, 2) void pair_main(
    const float* __restrict__ qp, const float* __restrict__ kp,
    const float* __restrict__ qv, const float* __restrict__ kv,
    const __hip_bfloat16* __restrict__ W1T, const __hip_bfloat16* __restrict__ W2T,
    const float* __restrict__ b0, const float* __restrict__ b1,
    const float* __restrict__ b2, const float* __restrict__ Wf,
    const float* __restrict__ bf_, const float* __restrict__ bv1,
    const float* __restrict__ Wv2, const float* __restrict__ bv2,
    float* __restrict__ out)
{
    extern __shared__ char smem[];
    char* hbuf = smem;             // 65536
    char* wbufs = smem + 65536;    // 3 x 16384

    const int t    = threadIdx.x;
    const int lane = t & 63, wave = t >> 6;
    const int wm   = wave >> 2, wn = wave & 3;
    const int idx  = blockIdx.x;
    const int q    = idx >> 3;            // 0..255
    const int kt   = idx & 3;             // 0..3
    const int b    = (idx >> 2) & 1;      // low 3 bits = (b,kt) -> per-XCD
    const int k0g  = kt * 128;

    const float* qprow  = qp + (size_t)(b * SQ_DIM + q) * H_DIM;
    const float* kprows = kp + (size_t)(b * SK_DIM + k0g) * H_DIM;

    // ---- stage W global-chunk g (0..15) into wbuf[g%3] via global_load_lds ----
    auto stage = [&](int g) {
        const __hip_bfloat16* Wsrc = (g < 8) ? W1T : W2T;
        char* wb = wbufs + (size_t)(g % 3) * 16384;
        const int k0 = (g & 7) * 32;
        #pragma unroll
        for (int i = 0; i < 2; ++i) {
            int u = wave * 64 + i * 512 + lane;      // 16B unit index 0..1023
            int n = u >> 2;
            int s_log = (u & 3) ^ ((n >> 1) & 3);    // inverse swizzle on source
            const __hip_bfloat16* gp = Wsrc + n * H_DIM + k0 + s_log * 8;
            char* lp = wb + (wave * 64 + i * 512) * 16;   // wave-uniform base
            __builtin_amdgcn_global_load_lds((const void*)gp, (void*)lp, 16, 0, 0);
        }
    };

    // ---- h0 = relu(qp + kp + b0) -> hbuf (bf16, swizzled) ----
    #pragma unroll
    for (int i = 0; i < 8; ++i) {
        int cidx = t + 512 * i;
        int row  = cidx >> 5;     // 0..127
        int c8   = cidx & 31;     // 8-elem group
        const float* kr = kprows + row * H_DIM + c8 * 8;
        f32x4 k0v = *(const f32x4*)(kr);
        f32x4 k1v = *(const f32x4*)(kr + 4);
        f32x4 q0v = *(const f32x4*)(qprow + c8 * 8);
        f32x4 q1v = *(const f32x4*)(qprow + c8 * 8 + 4);
        f32x4 z0  = *(const f32x4*)(b0 + c8 * 8);
        f32x4 z1  = *(const f32x4*)(b0 + c8 * 8 + 4);
        short8 pk;
        #pragma unroll
        for (int j = 0; j < 4; ++j) {
            float v = fmaxf(k0v[j] + q0v[j] + z0[j], 0.f);
            float w = fmaxf(k1v[j] + q1v[j] + z1[j], 0.f);
            __hip_bfloat16 hv = __float2bfloat16(v);
            __hip_bfloat16 hw = __float2bfloat16(w);
            pk[j]     = __builtin_bit_cast(short, hv);
            pk[j + 4] = __builtin_bit_cast(short, hw);
        }
        int addr = (row * 512 + c8 * 16) ^ ((row & 7) << 4);
        *(short8*)(hbuf + addr) = pk;
    }
    stage(0);
    stage(1);
    SCHED_FENCE();     // pin stage issues before the counted wait
    WAIT_VMCNT_2();    // MY stage(0) landed; symmetric waves => buf0 landed
    WAIT_LGKM_0();     // h0 ds_writes visible
    RAW_BARRIER();     // stage(1) loads remain in flight

    f32x4 acc[4][4];
    #pragma unroll
    for (int i = 0; i < 4; ++i)
        #pragma unroll
        for (int j = 0; j < 4; ++j)
            acc[i][j] = 0.f;

    // one K=32 body (precondition: buf g fully landed):
    //   ds_read+MFMA -> stage(g+2) -> vmcnt(2) -> lgkm0 -> barrier
    auto body = [&](int g) {
        const char* wb = wbufs + (size_t)(g % 3) * 16384;
        const int c = g & 7;
        short8 afrag[4];
        #pragma unroll
        for (int nt = 0; nt < 4; ++nt) {
            int n = 64 * wn + 16 * nt + (lane & 15);
            int s_lds = (lane >> 4) ^ ((n >> 1) & 3);
            afrag[nt] = *(const short8*)(wb + n * 64 + s_lds * 16);
        }
        #pragma unroll
        for (int mt = 0; mt < 4; ++mt) {
            int m = 64 * wm + 16 * mt + (lane & 15);
            int addr = (m * 512 + c * 64 + ((lane >> 4) * 16)) ^ ((m & 7) << 4);
            short8 bfrag = *(const short8*)(hbuf + addr);
            #pragma unroll
            for (int nt = 0; nt < 4; ++nt)
                acc[mt][nt] = __builtin_amdgcn_mfma_f32_16x16x32_bf16(afrag[nt], bfrag, acc[mt][nt], 0, 0, 0);
        }
        if (g + 2 < 16) stage(g + 2);   // overwrites buf read at body(g-1)
        SCHED_FENCE();                   // pin stage issue before the wait
        if (g < 14) { WAIT_VMCNT_2(); }  // stage(g+1) landed (mine); all waves
        else        { WAIT_VMCNT_0(); }  // tail: drain
        WAIT_LGKM_0();                   // my ds_reads done before barrier
        RAW_BARRIER();                   // => buf g+1 fully landed post-barrier
    };

    // ---- layer 1 (global chunks 0..7 = W1T) ----
    #pragma unroll
    for (int g = 0; g < 8; ++g)
        body(g);

    // ---- h1 = relu(D + b1) -> hbuf (post body(7) barrier: h0 reads done) ----
    #pragma unroll
    for (int mt = 0; mt < 4; ++mt) {
        int m = 64 * wm + 16 * mt + (lane & 15);
        #pragma unroll
        for (int nt = 0; nt < 4; ++nt) {
            int n0_ = 64 * wn + 16 * nt + ((lane >> 4) << 2);
            f32x4 bias = *(const f32x4*)(b1 + n0_);
            short4v pk;
            #pragma unroll
            for (int j = 0; j < 4; ++j) {
                float v = fmaxf(acc[mt][nt][j] + bias[j], 0.f);
                __hip_bfloat16 hv = __float2bfloat16(v);
                pk[j] = __builtin_bit_cast(short, hv);
            }
            int addr = (m * 512 + n0_ * 2) ^ ((m & 7) << 4);
            *(short4v*)(hbuf + addr) = pk;
            acc[mt][nt] = 0.f;
        }
    }
    WAIT_LGKM_0();     // h1 visible
    RAW_BARRIER();     // stage(9) loads still in flight (buf8 landed pre-body(7)-barrier)

    // ---- layer 2 (global chunks 8..15 = W2T) ----
    #pragma unroll
    for (int g = 8; g < 16; ++g)
        body(g);

    // ---- logits: sum_n relu(h2 + b2) * Wf  (+ bf) ----
    float p[4];
    #pragma unroll
    for (int mt = 0; mt < 4; ++mt) {
        float s = 0.f;
        #pragma unroll
        for (int nt = 0; nt < 4; ++nt) {
            int n0_ = 64 * wn + 16 * nt + ((lane >> 4) << 2);
            f32x4 wf   = *(const f32x4*)(Wf + n0_);
            f32x4 bias = *(const f32x4*)(b2 + n0_);
            #pragma unroll
            for (int j = 0; j < 4; ++j)
                s += fmaxf(acc[mt][nt][j] + bias[j], 0.f) * wf[j];
        }
        s += __shfl_xor(s, 16);
        s += __shfl_xor(s, 32);
        p[mt] = s;
    }

    float* lpart = (float*)smem;   // overwrite hbuf (all reads drained at body(15))
    if (lane < 16) {
        #pragma unroll
        for (int mt = 0; mt < 4; ++mt)
            lpart[(wm * 64 + mt * 16 + lane) * 4 + wn] = p[mt];
    }
    __syncthreads();

    const size_t obase = (size_t)(b * SQ_DIM + q) * SK_DIM + k0g;
    if (t < 128) {
        f32x4 v = *(const f32x4*)(lpart + t * 4);
        out[obase + t] = v[0] + v[1] + v[2] + v[3] + bf_[0];
    }

    // ---- variance: softplus(sum_c relu(qv+kv+bv1)*Wv2 + bv2), fp32 ----
    {
        int r = t >> 2, s4 = t & 3;
        const float* qvrow = qv + (size_t)(b * SQ_DIM + q) * H_DIM;
        const float* kvrow = kv + (size_t)(b * SK_DIM + k0g + r) * H_DIM;
        float a = 0.f;
        #pragma unroll
        for (int i = 0; i < 16; ++i) {
            int cidx = s4 * 64 + i * 4;
            f32x4 x  = *(const f32x4*)(qvrow + cidx);
            f32x4 y  = *(const f32x4*)(kvrow + cidx);
            f32x4 bb = *(const f32x4*)(bv1 + cidx);
            f32x4 wv = *(const f32x4*)(Wv2 + cidx);
            #pragma unroll
            for (int j = 0; j < 4; ++j)
                a += fmaxf(x[j] + y[j] + bb[j], 0.f) * wv[j];
        }
        a += __shfl_xor(a, 1);
        a += __shfl_xor(a, 2);
        if (s4 == 0) {
            float xx = a + bv2[0];
            float sp = (xx > 20.f) ? xx : log1pf(expf(xx));
            out[(size_t)B_DIM * SQ_DIM * SK_DIM + obase + r] = sp;
        }
    }
}

// ---------------------------------------------------------------------------
extern "C" void kernel_launch(void* const* d_in, const int* in_sizes, int n_in,
                              void* d_out, int out_size, void* d_ws, size_t ws_size,
                              hipStream_t stream)
{
    (void)in_sizes; (void)n_in; (void)out_size; (void)ws_size;

    const float* query = (const float*)d_in[0];
    const float* key   = (const float*)d_in[1];
    const float* Wqe   = (const float*)d_in[2];
    const float* bqe   = (const float*)d_in[3];
    const float* Wke   = (const float*)d_in[4];
    const float* bke   = (const float*)d_in[5];
    const float* W0    = (const float*)d_in[6];
    const float* b0    = (const float*)d_in[7];
    const float* W1    = (const float*)d_in[8];
    const float* b1    = (const float*)d_in[9];
    const float* W2    = (const float*)d_in[10];
    const float* b2    = (const float*)d_in[11];
    const float* Wf    = (const float*)d_in[12];
    const float* bf    = (const float*)d_in[13];
    const float* Wv1   = (const float*)d_in[14];
    const float* bv1   = (const float*)d_in[15];
    const float* Wv2   = (const float*)d_in[16];
    const float* bv2   = (const float*)d_in[17];
    float* out = (float*)d_out;

    char* ws = (char*)d_ws;
    // prep buffers (A1 region later reused by qpkp/qvkv — disjoint lifetimes)
    __hip_bfloat16* A1    = (__hip_bfloat16*)(ws);                 // 1536x1024 bf16 (3 MB)
    __hip_bfloat16* Aq    = (__hip_bfloat16*)(ws + 3145728);       // 1536x512 bf16 (1.5 MB)
    __hip_bfloat16* Benc  = (__hip_bfloat16*)(ws + 4718592);       // 2x256x1024 bf16 (1 MB)
    __hip_bfloat16* Bproj = (__hip_bfloat16*)(ws + 5767168);       // 2x512x512 bf16 (1 MB)
    __hip_bfloat16* W1T   = (__hip_bfloat16*)(ws + 6815744);       // 256x256 bf16
    __hip_bfloat16* W2T   = (__hip_bfloat16*)(ws + 6946816);       // 256x256 bf16
    float* qpkp = (float*)(ws);                                    // 1536x256 f32 (aliases A1)
    float* qvkv = (float*)(ws + 1572864);                          // 1536x256 f32

    const float* qp = qpkp;
    const float* kp = qpkp + 512 * 256;
    const float* qv = qvkv;
    const float* kv = qvkv + 512 * 256;

    // 112 KB dynamic LDS (hbuf 64K + 3 x 16K wbuf ring); 1 block/CU accepted
    (void)hipFuncSetAttribute((const void*)pair_main,
                              hipFuncAttributeMaxDynamicSharedMemorySize, 114688);

    transpose_split<<<dim3(32, 8), 256, 0, stream>>>(Wqe, Wke, W0, Wv1, W1, W2,
                                                     Benc, Bproj, W1T, W2T);
    split_cast<<<dim3(768), 256, 0, stream>>>(query, key, A1);
    // encoders: relu(A @ Wenc^T + bias) -> Aq (bf16 hi/lo)
    gemm3<512, true><<<dim3(4, 24), 256, 0, stream>>>(
        A1, Benc, Benc + 256 * 1024, bqe, bke, Aq, nullptr, nullptr);
    // projections: qpkp | qvkv (fp32), no bias
    gemm3<256, false><<<dim3(8, 24), 256, 0, stream>>>(
        Aq, Bproj, Bproj + 512 * 512, nullptr, nullptr, nullptr, qpkp, qvkv);
    // fused pair MLP + variance
    pair_main<<<dim3(2048), 512, 114688, stream>>>(qp, kp, qv, kv, W1T, W2T,
                                                   b0, b1, b2, Wf, bf, bv1, Wv2, bv2, out);
}